// Round 6
// baseline (178.762 us; speedup 1.0000x reference)
//
#include <hip/hip_runtime.h>

#define D 128
#define LDA 136     // bf16 elems per LDS row (+8 pad)
#define BCAP 64     // bucket capacity per dst (max degree ~35 for this data)
#define CSTRIDE 16  // counts padded: 1 counter per 64B line
#define OVCAP 65536 // overflow list capacity (correct fallback, empty in practice)

typedef __attribute__((ext_vector_type(8))) short bf16x8;
typedef __attribute__((ext_vector_type(4))) float f32x4;
typedef __attribute__((ext_vector_type(4))) unsigned int u32x4;

static __device__ __forceinline__ unsigned short f2bf(float f) {
    unsigned u = __float_as_uint(f);
    unsigned r = 0x7fffu + ((u >> 16) & 1u);   // round-to-nearest-even
    return (unsigned short)((u + r) >> 16);
}
static __device__ __forceinline__ float bflo(unsigned u) { return __uint_as_float(u << 16); }
static __device__ __forceinline__ float bfhi(unsigned u) { return __uint_as_float(u & 0xffff0000u); }

// ---------------------------------------------------------------------------
// zero_wt: replaces hipMemsetAsync (same dispatch count). Zeros counts +
// ovcnt with vector stores AND writes Wt[n][k] = bf16(W[k][n]) with
// COALESCED dword stores (reads uncoalesced but W is 64KB, cache-hot).
// (round-4 lesson: in-kernel LDS transpose = 32-way bank conflict, ~20us.)
// ---------------------------------------------------------------------------
__global__ __launch_bounds__(256) void zero_wt_kernel(
    const float* __restrict__ W, unsigned short* __restrict__ Wt,
    int* __restrict__ counts, int nz4)
{
    int i = blockIdx.x * 256 + threadIdx.x;
    if (i < nz4) ((u32x4*)counts)[i] = (u32x4){0u, 0u, 0u, 0u};
    if (i < 8192) {                          // 2 consecutive k per thread
        int n = i >> 6, k2 = (i & 63) << 1;
        unsigned lo = f2bf(W[(size_t)k2 * 128 + n]);
        unsigned hi = f2bf(W[(size_t)(k2 + 1) * 128 + n]);
        ((unsigned*)Wt)[(size_t)n * 64 + (k2 >> 1)] = lo | (hi << 16);
    }
}

// ---------------------------------------------------------------------------
// prep_gemm v3: (1) edge loads + count atomics FIRST (latency hides under
// GEMM), (2) WH = H@W tile via MFMA with A-fragments straight from H f32
// global and B-fragments straight from global Wt (32KB, L1-resident — no
// Wsh, no staging sync; round-5 lesson: 34KB LDS capped occupancy at 29%
// and cost +7us on the scattered-op phase), (3) per-wave bf16 C-bounce
// through a 17KB Csh slice (f2bf at write = identical rounding; each wave
// touches only its own rows -> ZERO __syncthreads), (4) coalesced WHb
// stores (PLAIN: keep L3-resident — round-3 lesson), (5) bucket stores.
// LDS 17408B + ~60 VGPR -> ~8 blocks/CU -> edge path gets its TLP back.
// ---------------------------------------------------------------------------
__global__ __launch_bounds__(256, 6) void prep_gemm_kernel(
    const float* __restrict__ H, int n_src,
    const unsigned short* __restrict__ Wt, unsigned short* __restrict__ WHb,
    const int* __restrict__ esrc, const int* __restrict__ edst, int E,
    int* __restrict__ counts, int* __restrict__ buckets,
    int* __restrict__ ovcnt, int* __restrict__ ovd, int* __restrict__ ovs)
{
    __shared__ __align__(16) unsigned short Csh[64 * LDA];   // 17408 B

    const int tid = threadIdx.x, bid = blockIdx.x;
    const int gt = (int)gridDim.x * 256;

    // --- edges: loads + atomics issued first ---
    int e0 = bid * 256 + tid, e1 = e0 + gt;
    bool h0 = (e0 < E), h1 = (e1 < E);
    int d0 = 0, s0 = 0, d1 = 0, s1 = 0, c0 = 0, c1 = 0;
    if (h0) { d0 = __builtin_nontemporal_load(edst + e0);
              s0 = __builtin_nontemporal_load(esrc + e0); }
    if (h1) { d1 = __builtin_nontemporal_load(edst + e1);
              s1 = __builtin_nontemporal_load(esrc + e1); }
    if (h0) c0 = atomicAdd(&counts[(size_t)d0 * CSTRIDE], 1);
    if (h1) c1 = atomicAdd(&counts[(size_t)d1 * CSTRIDE], 1);

    const int lane = tid & 63, wvid = tid >> 6;
    const int fl = lane & 15, quad = lane >> 4;
    const int rowbase = bid * 64;
    const int m0 = wvid * 16;

    if (rowbase < n_src) {
        // A-fragments straight from H: row = rowbase + m0 + fl,
        // cols kc + quad*8 .. +8 for kc in {0,32,64,96}
        int arow = rowbase + m0 + fl;
        bool rok = (arow < n_src);
        const f32x4* H4 = (const f32x4*)H;
        size_t base = (size_t)arow * 32 + quad * 2;
        f32x4 z = (f32x4){0.f, 0.f, 0.f, 0.f};
        f32x4 av0 = rok ? H4[base +  0] : z, av1 = rok ? H4[base +  1] : z;
        f32x4 av2 = rok ? H4[base +  8] : z, av3 = rok ? H4[base +  9] : z;
        f32x4 av4 = rok ? H4[base + 16] : z, av5 = rok ? H4[base + 17] : z;
        f32x4 av6 = rok ? H4[base + 24] : z, av7 = rok ? H4[base + 25] : z;

        f32x4 cacc[8];
#pragma unroll
        for (int n = 0; n < 8; ++n) cacc[n] = (f32x4){0.f, 0.f, 0.f, 0.f};

#define PACK_A(a, v0, v1)                                                    \
        { a[0] = (short)f2bf(v0.x); a[1] = (short)f2bf(v0.y);                \
          a[2] = (short)f2bf(v0.z); a[3] = (short)f2bf(v0.w);                \
          a[4] = (short)f2bf(v1.x); a[5] = (short)f2bf(v1.y);                \
          a[6] = (short)f2bf(v1.z); a[7] = (short)f2bf(v1.w); }
#define MSTEP(a, KC)                                                          \
        _Pragma("unroll")                                                     \
        for (int n = 0; n < 8; ++n) {                                         \
            bf16x8 bf = *(const bf16x8*)&Wt[(n * 16 + fl) * 128 + (KC) + quad * 8]; \
            cacc[n] = __builtin_amdgcn_mfma_f32_16x16x32_bf16(a, bf, cacc[n], 0, 0, 0); \
        }
        bf16x8 a0, a1, a2, a3;
        PACK_A(a0, av0, av1) PACK_A(a1, av2, av3)
        PACK_A(a2, av4, av5) PACK_A(a3, av6, av7)
        MSTEP(a0, 0) MSTEP(a1, 32) MSTEP(a2, 64) MSTEP(a3, 96)
#undef PACK_A
#undef MSTEP

        // per-wave bf16 C-bounce (own 16-row slice; no cross-wave sharing)
#pragma unroll
        for (int n = 0; n < 8; ++n) {
            int col = n * 16 + fl;
#pragma unroll
            for (int r = 0; r < 4; ++r)
                Csh[(m0 + quad * 4 + r) * LDA + col] = f2bf(cacc[n][r]);
        }
        // coalesced store of this wave's rows (compiler inserts lgkmcnt for
        // the same-wave LDS RAW; no barrier needed)
#pragma unroll
        for (int t = 0; t < 4; ++t) {
            int c = lane + t * 64;
            int row = m0 + (c >> 4), chunk = c & 15;
            size_t gr = (size_t)rowbase + row;
            if (gr < (size_t)n_src) {
                u32x4 v = *(const u32x4*)&Csh[row * LDA + chunk * 8];
                ((u32x4*)WHb)[gr * 16 + chunk] = v;   // PLAIN: keep L3-resident
            }
        }
    }

    // --- bucket stores (atomic results landed long ago) ---
    if (h0) {
        if (c0 < BCAP) buckets[(size_t)d0 * BCAP + c0] = s0;
        else { int o = atomicAdd(ovcnt, 1); if (o < OVCAP) { ovd[o] = d0; ovs[o] = s0; } }
    }
    if (h1) {
        if (c1 < BCAP) buckets[(size_t)d1 * BCAP + c1] = s1;
        else { int o = atomicAdd(ovcnt, 1); if (o < OVCAP) { ovd[o] = d1; ovs[o] = s1; } }
    }
    // cold remainder (only if E > 2*grid threads; empty here)
    for (int e = e0 + 2 * gt; e < E; e += gt) {
        int dd = edst[e], ss = esrc[e];
        int cc = atomicAdd(&counts[(size_t)dd * CSTRIDE], 1);
        if (cc < BCAP) buckets[(size_t)dd * BCAP + cc] = ss;
        else { int o = atomicAdd(ovcnt, 1); if (o < OVCAP) { ovd[o] = dd; ovs[o] = ss; } }
    }
}

// ---------------------------------------------------------------------------
// agg_finalize: one wave per dst row; gather WHb rows (verified loop), then
// out = relu(sum/max(deg,1) + (deg>0 ? b : 0)) written directly (nt, write-
// once). No LDS -> high occupancy for the latency-bound gather.
// ---------------------------------------------------------------------------
__global__ __launch_bounds__(256) void agg_finalize_kernel(
    const uint4* __restrict__ WHb, const int* __restrict__ buckets,
    const int* __restrict__ counts, const int* __restrict__ ovcnt,
    const int* __restrict__ ovd, const int* __restrict__ ovs,
    const float* __restrict__ b, float* __restrict__ out, int n_dst)
{
    int dst = blockIdx.x * 4 + (threadIdx.x >> 6);
    if (dst >= n_dst) return;
    int lane = threadIdx.x & 63;
    int dg = counts[(size_t)dst * CSTRIDE];
    int m = dg < BCAP ? dg : BCAP;
    int nov = *ovcnt; if (nov > OVCAP) nov = OVCAP;
    int idx = (lane < m) ? buckets[(size_t)dst * BCAP + lane] : 0;

    const int ql = lane & 15, quad = lane >> 4;
    float acc[8] = {0, 0, 0, 0, 0, 0, 0, 0};
    int j = 0;
    for (; j + 8 <= m; j += 8) {                 // 8 rows in flight
        int sA = __shfl(idx, j + quad);
        int sB = __shfl(idx, j + 4 + quad);
        uint4 ha = WHb[(size_t)sA * 16 + ql];
        uint4 hb = WHb[(size_t)sB * 16 + ql];
        acc[0] += bflo(ha.x) + bflo(hb.x); acc[1] += bfhi(ha.x) + bfhi(hb.x);
        acc[2] += bflo(ha.y) + bflo(hb.y); acc[3] += bfhi(ha.y) + bfhi(hb.y);
        acc[4] += bflo(ha.z) + bflo(hb.z); acc[5] += bfhi(ha.z) + bfhi(hb.z);
        acc[6] += bflo(ha.w) + bflo(hb.w); acc[7] += bfhi(ha.w) + bfhi(hb.w);
    }
    for (; j < m; j += 4) {                      // predicated tail
        int jj = j + quad;
        int s = __shfl(idx, jj < m ? jj : m - 1);
        uint4 hv = WHb[(size_t)s * 16 + ql];
        float w = (jj < m) ? 1.f : 0.f;
        acc[0] += w * bflo(hv.x); acc[1] += w * bfhi(hv.x);
        acc[2] += w * bflo(hv.y); acc[3] += w * bfhi(hv.y);
        acc[4] += w * bflo(hv.z); acc[5] += w * bfhi(hv.z);
        acc[6] += w * bflo(hv.w); acc[7] += w * bfhi(hv.w);
    }
    for (int k = quad; k < nov; k += 4) {        // overflow (empty normally)
        if (ovd[k] == dst) {
            uint4 hv = WHb[(size_t)ovs[k] * 16 + ql];
            acc[0] += bflo(hv.x); acc[1] += bfhi(hv.x);
            acc[2] += bflo(hv.y); acc[3] += bfhi(hv.y);
            acc[4] += bflo(hv.z); acc[5] += bfhi(hv.z);
            acc[6] += bflo(hv.w); acc[7] += bfhi(hv.w);
        }
    }
#pragma unroll
    for (int k = 0; k < 8; ++k) {
        acc[k] += __shfl_xor(acc[k], 16);
        acc[k] += __shfl_xor(acc[k], 32);
    }
    if (quad == 0) {
        float inv  = 1.0f / (float)(dg > 1 ? dg : 1);
        float gate = (dg > 0) ? 1.0f : 0.0f;
        const f32x4* b4 = (const f32x4*)b;
        f32x4 b0 = b4[ql * 2], b1 = b4[ql * 2 + 1];
        f32x4 o0, o1;
        o0.x = fmaxf(acc[0] * inv + b0.x * gate, 0.f);
        o0.y = fmaxf(acc[1] * inv + b0.y * gate, 0.f);
        o0.z = fmaxf(acc[2] * inv + b0.z * gate, 0.f);
        o0.w = fmaxf(acc[3] * inv + b0.w * gate, 0.f);
        o1.x = fmaxf(acc[4] * inv + b1.x * gate, 0.f);
        o1.y = fmaxf(acc[5] * inv + b1.y * gate, 0.f);
        o1.z = fmaxf(acc[6] * inv + b1.z * gate, 0.f);
        o1.w = fmaxf(acc[7] * inv + b1.w * gate, 0.f);
        f32x4* op = (f32x4*)out + (size_t)dst * 32 + ql * 2;
        __builtin_nontemporal_store(o0, op);
        __builtin_nontemporal_store(o1, op + 1);
    }
}

// ---------------------------------------------------------------------------
// Fallback path (workspace too small for WHb): edges-only prep, f32 gather,
// MFMA gemm_finalize (Wt comes from zero_wt). Verified in earlier rounds.
// ---------------------------------------------------------------------------
__global__ __launch_bounds__(256) void prep_fb_kernel(
    const int* __restrict__ esrc, const int* __restrict__ edst, int E,
    int* __restrict__ counts, int* __restrict__ buckets,
    int* __restrict__ ovcnt, int* __restrict__ ovd, int* __restrict__ ovs)
{
    int i = blockIdx.x * 256 + threadIdx.x;
    if (i >= E) return;
    int d = edst[i], s = esrc[i];
    int c = atomicAdd(&counts[(size_t)d * CSTRIDE], 1);
    if (c < BCAP) buckets[(size_t)d * BCAP + c] = s;
    else { int o = atomicAdd(ovcnt, 1); if (o < OVCAP) { ovd[o] = d; ovs[o] = s; } }
}

__global__ __launch_bounds__(256) void aggregate_kernel_f32(
    const float* __restrict__ H,
    const int* __restrict__ buckets, const int* __restrict__ counts,
    const int* __restrict__ ovcnt, const int* __restrict__ ovd,
    const int* __restrict__ ovs, unsigned short* __restrict__ aggb, int n_dst)
{
    int dst = blockIdx.x * 4 + (threadIdx.x >> 6);
    if (dst >= n_dst) return;
    int lane = threadIdx.x & 63;
    int dg = counts[(size_t)dst * CSTRIDE];
    int m = dg < BCAP ? dg : BCAP;
    int nov = *ovcnt; if (nov > OVCAP) nov = OVCAP;
    int idx = (lane < m) ? buckets[(size_t)dst * BCAP + lane] : 0;

    const int hl = lane & 31, half = lane >> 5;
    const float4* H4 = (const float4*)H;
    float acc[4] = {0, 0, 0, 0};
    int j = 0;
    for (; j + 4 <= m; j += 4) {
        int sA = __shfl(idx, j + half);
        int sB = __shfl(idx, j + 2 + half);
        float4 va = H4[(size_t)sA * 32 + hl];
        float4 vb = H4[(size_t)sB * 32 + hl];
        acc[0] += va.x + vb.x; acc[1] += va.y + vb.y;
        acc[2] += va.z + vb.z; acc[3] += va.w + vb.w;
    }
    for (; j < m; j += 2) {
        int jj = j + half;
        int s = __shfl(idx, jj < m ? jj : m - 1);
        float4 v = H4[(size_t)s * 32 + hl];
        float w = (jj < m) ? 1.f : 0.f;
        acc[0] += w * v.x; acc[1] += w * v.y;
        acc[2] += w * v.z; acc[3] += w * v.w;
    }
    for (int k = half; k < nov; k += 2) {
        if (ovd[k] == dst) {
            float4 v = H4[(size_t)ovs[k] * 32 + hl];
            acc[0] += v.x; acc[1] += v.y; acc[2] += v.z; acc[3] += v.w;
        }
    }
#pragma unroll
    for (int k = 0; k < 4; ++k) acc[k] += __shfl_xor(acc[k], 32);
    if (half == 0) {
        uint2 o;
        o.x = (unsigned)f2bf(acc[0]) | ((unsigned)f2bf(acc[1]) << 16);
        o.y = (unsigned)f2bf(acc[2]) | ((unsigned)f2bf(acc[3]) << 16);
        ((uint2*)aggb)[(size_t)dst * 32 + hl] = o;
    }
}

__global__ __launch_bounds__(256) void gemm_finalize_kernel(
    const unsigned short* __restrict__ aggb, const unsigned short* __restrict__ Wt,
    const float* __restrict__ b, const int* __restrict__ counts,
    float* __restrict__ out, int n_dst)
{
    __shared__ __align__(16) unsigned char smem[52224];
    unsigned short* Ash = (unsigned short*)smem;                   // [64][LDA]
    unsigned short* Wsh = (unsigned short*)(smem + 64 * LDA * 2);  // [128][LDA]
    float* Csh = (float*)smem;                                     // [64][132]

    const int tid  = threadIdx.x;
    const int lane = tid & 63, wv = tid >> 6;
    const size_t row0 = (size_t)blockIdx.x * 64;

#pragma unroll
    for (int t = 0; t < 4; ++t) {
        int i = tid + t * 256;
        int r = i >> 4, k8 = (i & 15) << 3;
        size_t gr = row0 + r;
        uint4 v = (gr < (size_t)n_dst) ? ((const uint4*)aggb)[gr * 16 + (i & 15)]
                                       : make_uint4(0, 0, 0, 0);
        *(uint4*)&Ash[r * LDA + k8] = v;
    }
#pragma unroll
    for (int t = 0; t < 8; ++t) {
        int i = tid + t * 256;
        int n = i >> 4, k8 = (i & 15) << 3;
        *(uint4*)&Wsh[n * LDA + k8] = ((const uint4*)Wt)[i];
    }
    __syncthreads();

    const int m0 = wv * 16;
    const int fl = lane & 15, quad = lane >> 4;

    f32x4 cacc[8];
#pragma unroll
    for (int n = 0; n < 8; ++n) cacc[n] = (f32x4){0.f, 0.f, 0.f, 0.f};

#pragma unroll
    for (int kc = 0; kc < 128; kc += 32) {
        bf16x8 a = *(const bf16x8*)&Ash[(m0 + fl) * LDA + kc + quad * 8];
#pragma unroll
        for (int n = 0; n < 8; ++n) {
            bf16x8 bf = *(const bf16x8*)&Wsh[(n * 16 + fl) * LDA + kc + quad * 8];
            cacc[n] = __builtin_amdgcn_mfma_f32_16x16x32_bf16(a, bf, cacc[n], 0, 0, 0);
        }
    }

    float inv[4], gate[4];
#pragma unroll
    for (int r = 0; r < 4; ++r) {
        size_t gr = row0 + m0 + quad * 4 + r;
        int dg = (gr < (size_t)n_dst) ? counts[gr * CSTRIDE] : 0;
        inv[r]  = 1.0f / (float)(dg > 1 ? dg : 1);
        gate[r] = (dg > 0) ? 1.0f : 0.0f;
    }
    __syncthreads();   // Ash/Wsh dead; reuse as Csh

#pragma unroll
    for (int n = 0; n < 8; ++n) {
        int col = n * 16 + fl;
        float bc = b[col];
#pragma unroll
        for (int r = 0; r < 4; ++r) {
            float v = cacc[n][r] * inv[r] + bc * gate[r];
            Csh[(m0 + quad * 4 + r) * 132 + col] = fmaxf(v, 0.0f);
        }
    }
    __syncthreads();

#pragma unroll
    for (int t = 0; t < 8; ++t) {
        int i = tid + t * 256;
        int rr = i >> 5, c4 = i & 31;
        size_t gr = row0 + rr;
        if (gr < (size_t)n_dst) {
            f32x4 vout = *(f32x4*)&Csh[rr * 132 + c4 * 4];
            __builtin_nontemporal_store(vout, (f32x4*)out + gr * (D / 4) + c4);
        }
    }
}

extern "C" void kernel_launch(void* const* d_in, const int* in_sizes, int n_in,
                              void* d_out, int out_size, void* d_ws, size_t ws_size,
                              hipStream_t stream) {
    const float* H    = (const float*)d_in[0];   // [N_src, 128]
    const float* W    = (const float*)d_in[1];   // [128, 128]
    const float* b    = (const float*)d_in[2];   // [128]
    const int*   esrc = (const int*)d_in[3];     // [E]
    const int*   edst = (const int*)d_in[4];     // [E]
    const int    E     = in_sizes[3];
    const int    n_dst = out_size / D;
    const int    nsrc_elems = in_sizes[0];       // N_src * 128
    const int    n_src = nsrc_elems / D;

    float* out = (float*)d_out;

    // ws: Wt | counts(padded) | ovcnt(pad) | ovd | ovs | buckets | aggb | WHb
    char* p = (char*)d_ws;
    unsigned short* Wt = (unsigned short*)p;  p += 128 * 128 * sizeof(unsigned short);
    int* counts = (int*)p;  p += (size_t)n_dst * CSTRIDE * 4;
    int* ovcnt  = (int*)p;  p += 256;            // zeroed together with counts
    int* ovd    = (int*)p;  p += (size_t)OVCAP * 4;
    int* ovs    = (int*)p;  p += (size_t)OVCAP * 4;
    int* buckets= (int*)p;  p += (size_t)n_dst * BCAP * 4;
    size_t agg_off = (((size_t)(p - (char*)d_ws)) + 255) & ~(size_t)255;
    unsigned short* aggb = (unsigned short*)((char*)d_ws + agg_off);
    size_t wh_off = (agg_off + (size_t)n_dst * D * 2 + 255) & ~(size_t)255;
    bool use_wh = (ws_size >= wh_off + (size_t)nsrc_elems * 2);
    unsigned short* WHb = (unsigned short*)((char*)d_ws + wh_off);

    // Zero counts+ovcnt AND transpose W->Wt bf16 in one dispatch.
    int nz4 = (n_dst * CSTRIDE + 64) / 4;
    int gz = nz4 > 8192 ? nz4 : 8192;
    zero_wt_kernel<<<(gz + 255) / 256, 256, 0, stream>>>(W, Wt, counts, nz4);

    if (use_wh) {
        int G = (n_src + 63) / 64;
        int Ge = (E + 511) / 512;
        if (Ge > G) G = Ge;
        prep_gemm_kernel<<<G, 256, 0, stream>>>(
            H, n_src, Wt, WHb, esrc, edst, E, counts, buckets, ovcnt, ovd, ovs);
        agg_finalize_kernel<<<(n_dst + 3) / 4, 256, 0, stream>>>(
            (const uint4*)WHb, buckets, counts, ovcnt, ovd, ovs, b, out, n_dst);
    } else {
        prep_fb_kernel<<<(E + 255) / 256, 256, 0, stream>>>(
            esrc, edst, E, counts, buckets, ovcnt, ovd, ovs);
        aggregate_kernel_f32<<<(n_dst + 3) / 4, 256, 0, stream>>>(
            H, buckets, counts, ovcnt, ovd, ovs, aggb, n_dst);
        gemm_finalize_kernel<<<(n_dst + 63) / 64, 256, 0, stream>>>(
            aggb, Wt, b, counts, out, n_dst);
    }
}

// Round 7
// 160.604 us; speedup vs baseline: 1.1131x; 1.1131x over previous
//
#include <hip/hip_runtime.h>

#define D 128
#define LDA 136     // bf16 elems per LDS row (+8 pad)
#define BCAP 64     // bucket capacity per dst (max degree ~35 for this data)
#define CSTRIDE 16  // counts padded: 1 counter per 64B line
#define OVCAP 65536 // overflow list capacity (correct fallback, empty in practice)

typedef __attribute__((ext_vector_type(8))) short bf16x8;
typedef __attribute__((ext_vector_type(4))) float f32x4;
typedef __attribute__((ext_vector_type(4))) unsigned int u32x4;

static __device__ __forceinline__ unsigned short f2bf(float f) {
    unsigned u = __float_as_uint(f);
    unsigned r = 0x7fffu + ((u >> 16) & 1u);   // round-to-nearest-even
    return (unsigned short)((u + r) >> 16);
}
static __device__ __forceinline__ float bflo(unsigned u) { return __uint_as_float(u << 16); }
static __device__ __forceinline__ float bfhi(unsigned u) { return __uint_as_float(u & 0xffff0000u); }

// ---------------------------------------------------------------------------
// zero_wt: replaces hipMemsetAsync (same dispatch count). Zeros counts +
// ovcnt with vector stores AND writes Wt[n][k] = bf16(W[k][n]) with
// COALESCED dword stores. (round-4 lesson: in-kernel LDS transpose = 32-way
// bank conflict, ~20us.)
// ---------------------------------------------------------------------------
__global__ __launch_bounds__(256) void zero_wt_kernel(
    const float* __restrict__ W, unsigned short* __restrict__ Wt,
    int* __restrict__ counts, int nz4)
{
    int i = blockIdx.x * 256 + threadIdx.x;
    if (i < nz4) ((u32x4*)counts)[i] = (u32x4){0u, 0u, 0u, 0u};
    if (i < 8192) {                          // 2 consecutive k per thread
        int n = i >> 6, k2 = (i & 63) << 1;
        unsigned lo = f2bf(W[(size_t)k2 * 128 + n]);
        unsigned hi = f2bf(W[(size_t)(k2 + 1) * 128 + n]);
        ((unsigned*)Wt)[(size_t)n * 64 + (k2 >> 1)] = lo | (hi << 16);
    }
}

// ---------------------------------------------------------------------------
// prep_gemm v4: two-pass half-W GEMM. (1) edge loads + count atomics FIRST,
// (2) stage HALF of Wt into Wsh_h[64][LDA] (17408B LDS -> 6 blocks/CU; W
// must be in LDS: round-6 lesson — B-frags from global put L2 latency on
// the MFMA critical path, +14us), issue A-loads from H before the barrier
// so HBM latency drains with staging, (3) MFMA pass over output cols 0..63,
// barrier, restage cols 64..127, pass 2 (A-frags reused from regs), (4)
// per-wave bf16 Csh bounce (overlay, no barrier) -> coalesced PLAIN WHb
// stores (round-3 lesson: nt stores break L3 residency), (5) bucket stores.
// ---------------------------------------------------------------------------
__global__ __launch_bounds__(256, 6) void prep_gemm_kernel(
    const float* __restrict__ H, int n_src,
    const unsigned short* __restrict__ Wt, unsigned short* __restrict__ WHb,
    const int* __restrict__ esrc, const int* __restrict__ edst, int E,
    int* __restrict__ counts, int* __restrict__ buckets,
    int* __restrict__ ovcnt, int* __restrict__ ovd, int* __restrict__ ovs)
{
    __shared__ __align__(16) unsigned short Wsh[64 * LDA];   // 17408 B; Csh overlay

    const int tid = threadIdx.x, bid = blockIdx.x;
    const int gt = (int)gridDim.x * 256;

    // --- edges: loads + atomics issued first ---
    int e0 = bid * 256 + tid, e1 = e0 + gt;
    bool h0 = (e0 < E), h1 = (e1 < E);
    int d0 = 0, s0 = 0, d1 = 0, s1 = 0, c0 = 0, c1 = 0;
    if (h0) { d0 = __builtin_nontemporal_load(edst + e0);
              s0 = __builtin_nontemporal_load(esrc + e0); }
    if (h1) { d1 = __builtin_nontemporal_load(edst + e1);
              s1 = __builtin_nontemporal_load(esrc + e1); }
    if (h0) c0 = atomicAdd(&counts[(size_t)d0 * CSTRIDE], 1);
    if (h1) c1 = atomicAdd(&counts[(size_t)d1 * CSTRIDE], 1);

    const int lane = tid & 63, wvid = tid >> 6;
    const int fl = lane & 15, quad = lane >> 4;
    const int rowbase = bid * 64;
    const int m0 = wvid * 16;
    const bool doG = (rowbase < n_src);

    // --- stage Wsh half 0 (cols 0..63): b128, conflict-light ---
#pragma unroll
    for (int t = 0; t < 4; ++t) {
        int i = tid + t * 256;
        int nn = i >> 4, k8 = (i & 15) << 3;
        *(uint4*)&Wsh[nn * LDA + k8] = ((const uint4*)Wt)[nn * 16 + (i & 15)];
    }

    // --- A-loads issued before barrier: HBM latency drains with staging ---
    int arow = rowbase + m0 + fl;
    bool rok = doG && (arow < n_src);
    const f32x4* H4 = (const f32x4*)H;
    size_t base = (size_t)(rok ? arow : 0) * 32 + quad * 2;
    f32x4 z = (f32x4){0.f, 0.f, 0.f, 0.f};
    f32x4 av0 = z, av1 = z, av2 = z, av3 = z, av4 = z, av5 = z, av6 = z, av7 = z;
    if (rok) {
        av0 = H4[base +  0]; av1 = H4[base +  1];
        av2 = H4[base +  8]; av3 = H4[base +  9];
        av4 = H4[base + 16]; av5 = H4[base + 17];
        av6 = H4[base + 24]; av7 = H4[base + 25];
    }
    __syncthreads();

    f32x4 cacc[8];
#pragma unroll
    for (int n = 0; n < 8; ++n) cacc[n] = (f32x4){0.f, 0.f, 0.f, 0.f};

#define PACK_A(a, v0, v1)                                                    \
    { a[0] = (short)f2bf(v0.x); a[1] = (short)f2bf(v0.y);                    \
      a[2] = (short)f2bf(v0.z); a[3] = (short)f2bf(v0.w);                    \
      a[4] = (short)f2bf(v1.x); a[5] = (short)f2bf(v1.y);                    \
      a[6] = (short)f2bf(v1.z); a[7] = (short)f2bf(v1.w); }
#define MSTEP(a, KC, NL, CI)                                                  \
    { bf16x8 bf = *(const bf16x8*)&Wsh[((NL) * 16 + fl) * LDA + (KC) + quad * 8]; \
      cacc[CI] = __builtin_amdgcn_mfma_f32_16x16x32_bf16(a, bf, cacc[CI], 0, 0, 0); }

    bf16x8 a0, a1, a2, a3;
    PACK_A(a0, av0, av1) PACK_A(a1, av2, av3)
    PACK_A(a2, av4, av5) PACK_A(a3, av6, av7)

    if (doG) {
#pragma unroll
        for (int nl = 0; nl < 4; ++nl) {
            MSTEP(a0, 0, nl, nl) MSTEP(a1, 32, nl, nl)
            MSTEP(a2, 64, nl, nl) MSTEP(a3, 96, nl, nl)
        }
    }
    __syncthreads();   // Wsh half-0 dead

    // --- stage Wsh half 1 (cols 64..127) ---
#pragma unroll
    for (int t = 0; t < 4; ++t) {
        int i = tid + t * 256;
        int nn = i >> 4, k8 = (i & 15) << 3;
        *(uint4*)&Wsh[nn * LDA + k8] = ((const uint4*)Wt)[(64 + nn) * 16 + (i & 15)];
    }
    __syncthreads();

    if (doG) {
#pragma unroll
        for (int nl = 0; nl < 4; ++nl) {
            MSTEP(a0, 0, nl, nl + 4) MSTEP(a1, 32, nl, nl + 4)
            MSTEP(a2, 64, nl, nl + 4) MSTEP(a3, 96, nl, nl + 4)
        }
    }
    __syncthreads();   // Wsh dead; overlay Csh (per-wave slices, no more barriers)
#undef PACK_A
#undef MSTEP

    if (doG) {
        unsigned short* Csh = Wsh;   // [64][LDA] bf16 overlay
        // per-wave bf16 C-bounce (own 16-row slice; no cross-wave sharing)
#pragma unroll
        for (int n = 0; n < 8; ++n) {
            int col = n * 16 + fl;
#pragma unroll
            for (int r = 0; r < 4; ++r)
                Csh[(m0 + quad * 4 + r) * LDA + col] = f2bf(cacc[n][r]);
        }
        // coalesced store of this wave's rows (same-wave LDS RAW: compiler
        // inserts lgkmcnt; no barrier needed)
#pragma unroll
        for (int t = 0; t < 4; ++t) {
            int c = lane + t * 64;
            int row = m0 + (c >> 4), chunk = c & 15;
            size_t gr = (size_t)rowbase + row;
            if (gr < (size_t)n_src) {
                u32x4 v = *(const u32x4*)&Csh[row * LDA + chunk * 8];
                ((u32x4*)WHb)[gr * 16 + chunk] = v;   // PLAIN: keep L3-resident
            }
        }
    }

    // --- bucket stores (atomic results landed long ago) ---
    if (h0) {
        if (c0 < BCAP) buckets[(size_t)d0 * BCAP + c0] = s0;
        else { int o = atomicAdd(ovcnt, 1); if (o < OVCAP) { ovd[o] = d0; ovs[o] = s0; } }
    }
    if (h1) {
        if (c1 < BCAP) buckets[(size_t)d1 * BCAP + c1] = s1;
        else { int o = atomicAdd(ovcnt, 1); if (o < OVCAP) { ovd[o] = d1; ovs[o] = s1; } }
    }
    // cold remainder (only if E > 2*grid threads; empty here)
    for (int e = e0 + 2 * gt; e < E; e += gt) {
        int dd = edst[e], ss = esrc[e];
        int cc = atomicAdd(&counts[(size_t)dd * CSTRIDE], 1);
        if (cc < BCAP) buckets[(size_t)dd * BCAP + cc] = ss;
        else { int o = atomicAdd(ovcnt, 1); if (o < OVCAP) { ovd[o] = dd; ovs[o] = ss; } }
    }
}

// ---------------------------------------------------------------------------
// agg_finalize: one wave per dst row; gather WHb rows (verified loop), then
// out = relu(sum/max(deg,1) + (deg>0 ? b : 0)) written directly (nt, write-
// once). No LDS -> high occupancy for the latency-bound gather.
// ---------------------------------------------------------------------------
__global__ __launch_bounds__(256) void agg_finalize_kernel(
    const uint4* __restrict__ WHb, const int* __restrict__ buckets,
    const int* __restrict__ counts, const int* __restrict__ ovcnt,
    const int* __restrict__ ovd, const int* __restrict__ ovs,
    const float* __restrict__ b, float* __restrict__ out, int n_dst)
{
    int dst = blockIdx.x * 4 + (threadIdx.x >> 6);
    if (dst >= n_dst) return;
    int lane = threadIdx.x & 63;
    int dg = counts[(size_t)dst * CSTRIDE];
    int m = dg < BCAP ? dg : BCAP;
    int nov = *ovcnt; if (nov > OVCAP) nov = OVCAP;
    int idx = (lane < m) ? buckets[(size_t)dst * BCAP + lane] : 0;

    const int ql = lane & 15, quad = lane >> 4;
    float acc[8] = {0, 0, 0, 0, 0, 0, 0, 0};
    int j = 0;
    for (; j + 8 <= m; j += 8) {                 // 8 rows in flight
        int sA = __shfl(idx, j + quad);
        int sB = __shfl(idx, j + 4 + quad);
        uint4 ha = WHb[(size_t)sA * 16 + ql];
        uint4 hb = WHb[(size_t)sB * 16 + ql];
        acc[0] += bflo(ha.x) + bflo(hb.x); acc[1] += bfhi(ha.x) + bfhi(hb.x);
        acc[2] += bflo(ha.y) + bflo(hb.y); acc[3] += bfhi(ha.y) + bfhi(hb.y);
        acc[4] += bflo(ha.z) + bflo(hb.z); acc[5] += bfhi(ha.z) + bfhi(hb.z);
        acc[6] += bflo(ha.w) + bflo(hb.w); acc[7] += bfhi(ha.w) + bfhi(hb.w);
    }
    for (; j < m; j += 4) {                      // predicated tail
        int jj = j + quad;
        int s = __shfl(idx, jj < m ? jj : m - 1);
        uint4 hv = WHb[(size_t)s * 16 + ql];
        float w = (jj < m) ? 1.f : 0.f;
        acc[0] += w * bflo(hv.x); acc[1] += w * bfhi(hv.x);
        acc[2] += w * bflo(hv.y); acc[3] += w * bfhi(hv.y);
        acc[4] += w * bflo(hv.z); acc[5] += w * bfhi(hv.z);
        acc[6] += w * bflo(hv.w); acc[7] += w * bfhi(hv.w);
    }
    for (int k = quad; k < nov; k += 4) {        // overflow (empty normally)
        if (ovd[k] == dst) {
            uint4 hv = WHb[(size_t)ovs[k] * 16 + ql];
            acc[0] += bflo(hv.x); acc[1] += bfhi(hv.x);
            acc[2] += bflo(hv.y); acc[3] += bfhi(hv.y);
            acc[4] += bflo(hv.z); acc[5] += bfhi(hv.z);
            acc[6] += bflo(hv.w); acc[7] += bfhi(hv.w);
        }
    }
#pragma unroll
    for (int k = 0; k < 8; ++k) {
        acc[k] += __shfl_xor(acc[k], 16);
        acc[k] += __shfl_xor(acc[k], 32);
    }
    if (quad == 0) {
        float inv  = 1.0f / (float)(dg > 1 ? dg : 1);
        float gate = (dg > 0) ? 1.0f : 0.0f;
        const f32x4* b4 = (const f32x4*)b;
        f32x4 b0 = b4[ql * 2], b1 = b4[ql * 2 + 1];
        f32x4 o0, o1;
        o0.x = fmaxf(acc[0] * inv + b0.x * gate, 0.f);
        o0.y = fmaxf(acc[1] * inv + b0.y * gate, 0.f);
        o0.z = fmaxf(acc[2] * inv + b0.z * gate, 0.f);
        o0.w = fmaxf(acc[3] * inv + b0.w * gate, 0.f);
        o1.x = fmaxf(acc[4] * inv + b1.x * gate, 0.f);
        o1.y = fmaxf(acc[5] * inv + b1.y * gate, 0.f);
        o1.z = fmaxf(acc[6] * inv + b1.z * gate, 0.f);
        o1.w = fmaxf(acc[7] * inv + b1.w * gate, 0.f);
        f32x4* op = (f32x4*)out + (size_t)dst * 32 + ql * 2;
        __builtin_nontemporal_store(o0, op);
        __builtin_nontemporal_store(o1, op + 1);
    }
}

// ---------------------------------------------------------------------------
// Fallback path (workspace too small for WHb): edges-only prep, f32 gather,
// MFMA gemm_finalize (Wt comes from zero_wt). Verified in earlier rounds.
// ---------------------------------------------------------------------------
__global__ __launch_bounds__(256) void prep_fb_kernel(
    const int* __restrict__ esrc, const int* __restrict__ edst, int E,
    int* __restrict__ counts, int* __restrict__ buckets,
    int* __restrict__ ovcnt, int* __restrict__ ovd, int* __restrict__ ovs)
{
    int i = blockIdx.x * 256 + threadIdx.x;
    if (i >= E) return;
    int d = edst[i], s = esrc[i];
    int c = atomicAdd(&counts[(size_t)d * CSTRIDE], 1);
    if (c < BCAP) buckets[(size_t)d * BCAP + c] = s;
    else { int o = atomicAdd(ovcnt, 1); if (o < OVCAP) { ovd[o] = d; ovs[o] = s; } }
}

__global__ __launch_bounds__(256) void aggregate_kernel_f32(
    const float* __restrict__ H,
    const int* __restrict__ buckets, const int* __restrict__ counts,
    const int* __restrict__ ovcnt, const int* __restrict__ ovd,
    const int* __restrict__ ovs, unsigned short* __restrict__ aggb, int n_dst)
{
    int dst = blockIdx.x * 4 + (threadIdx.x >> 6);
    if (dst >= n_dst) return;
    int lane = threadIdx.x & 63;
    int dg = counts[(size_t)dst * CSTRIDE];
    int m = dg < BCAP ? dg : BCAP;
    int nov = *ovcnt; if (nov > OVCAP) nov = OVCAP;
    int idx = (lane < m) ? buckets[(size_t)dst * BCAP + lane] : 0;

    const int hl = lane & 31, half = lane >> 5;
    const float4* H4 = (const float4*)H;
    float acc[4] = {0, 0, 0, 0};
    int j = 0;
    for (; j + 4 <= m; j += 4) {
        int sA = __shfl(idx, j + half);
        int sB = __shfl(idx, j + 2 + half);
        float4 va = H4[(size_t)sA * 32 + hl];
        float4 vb = H4[(size_t)sB * 32 + hl];
        acc[0] += va.x + vb.x; acc[1] += va.y + vb.y;
        acc[2] += va.z + vb.z; acc[3] += va.w + vb.w;
    }
    for (; j < m; j += 2) {
        int jj = j + half;
        int s = __shfl(idx, jj < m ? jj : m - 1);
        float4 v = H4[(size_t)s * 32 + hl];
        float w = (jj < m) ? 1.f : 0.f;
        acc[0] += w * v.x; acc[1] += w * v.y;
        acc[2] += w * v.z; acc[3] += w * v.w;
    }
    for (int k = half; k < nov; k += 2) {
        if (ovd[k] == dst) {
            float4 v = H4[(size_t)ovs[k] * 32 + hl];
            acc[0] += v.x; acc[1] += v.y; acc[2] += v.z; acc[3] += v.w;
        }
    }
#pragma unroll
    for (int k = 0; k < 4; ++k) acc[k] += __shfl_xor(acc[k], 32);
    if (half == 0) {
        uint2 o;
        o.x = (unsigned)f2bf(acc[0]) | ((unsigned)f2bf(acc[1]) << 16);
        o.y = (unsigned)f2bf(acc[2]) | ((unsigned)f2bf(acc[3]) << 16);
        ((uint2*)aggb)[(size_t)dst * 32 + hl] = o;
    }
}

__global__ __launch_bounds__(256) void gemm_finalize_kernel(
    const unsigned short* __restrict__ aggb, const unsigned short* __restrict__ Wt,
    const float* __restrict__ b, const int* __restrict__ counts,
    float* __restrict__ out, int n_dst)
{
    __shared__ __align__(16) unsigned char smem[52224];
    unsigned short* Ash = (unsigned short*)smem;                   // [64][LDA]
    unsigned short* Wsh = (unsigned short*)(smem + 64 * LDA * 2);  // [128][LDA]
    float* Csh = (float*)smem;                                     // [64][132]

    const int tid  = threadIdx.x;
    const int lane = tid & 63, wv = tid >> 6;
    const size_t row0 = (size_t)blockIdx.x * 64;

#pragma unroll
    for (int t = 0; t < 4; ++t) {
        int i = tid + t * 256;
        int r = i >> 4, k8 = (i & 15) << 3;
        size_t gr = row0 + r;
        uint4 v = (gr < (size_t)n_dst) ? ((const uint4*)aggb)[gr * 16 + (i & 15)]
                                       : make_uint4(0, 0, 0, 0);
        *(uint4*)&Ash[r * LDA + k8] = v;
    }
#pragma unroll
    for (int t = 0; t < 8; ++t) {
        int i = tid + t * 256;
        int n = i >> 4, k8 = (i & 15) << 3;
        *(uint4*)&Wsh[n * LDA + k8] = ((const uint4*)Wt)[i];
    }
    __syncthreads();

    const int m0 = wv * 16;
    const int fl = lane & 15, quad = lane >> 4;

    f32x4 cacc[8];
#pragma unroll
    for (int n = 0; n < 8; ++n) cacc[n] = (f32x4){0.f, 0.f, 0.f, 0.f};

#pragma unroll
    for (int kc = 0; kc < 128; kc += 32) {
        bf16x8 a = *(const bf16x8*)&Ash[(m0 + fl) * LDA + kc + quad * 8];
#pragma unroll
        for (int n = 0; n < 8; ++n) {
            bf16x8 bf = *(const bf16x8*)&Wsh[(n * 16 + fl) * LDA + kc + quad * 8];
            cacc[n] = __builtin_amdgcn_mfma_f32_16x16x32_bf16(a, bf, cacc[n], 0, 0, 0);
        }
    }

    float inv[4], gate[4];
#pragma unroll
    for (int r = 0; r < 4; ++r) {
        size_t gr = row0 + m0 + quad * 4 + r;
        int dg = (gr < (size_t)n_dst) ? counts[gr * CSTRIDE] : 0;
        inv[r]  = 1.0f / (float)(dg > 1 ? dg : 1);
        gate[r] = (dg > 0) ? 1.0f : 0.0f;
    }
    __syncthreads();   // Ash/Wsh dead; reuse as Csh

#pragma unroll
    for (int n = 0; n < 8; ++n) {
        int col = n * 16 + fl;
        float bc = b[col];
#pragma unroll
        for (int r = 0; r < 4; ++r) {
            float v = cacc[n][r] * inv[r] + bc * gate[r];
            Csh[(m0 + quad * 4 + r) * 132 + col] = fmaxf(v, 0.0f);
        }
    }
    __syncthreads();

#pragma unroll
    for (int t = 0; t < 8; ++t) {
        int i = tid + t * 256;
        int rr = i >> 5, c4 = i & 31;
        size_t gr = row0 + rr;
        if (gr < (size_t)n_dst) {
            f32x4 vout = *(f32x4*)&Csh[rr * 132 + c4 * 4];
            __builtin_nontemporal_store(vout, (f32x4*)out + gr * (D / 4) + c4);
        }
    }
}

extern "C" void kernel_launch(void* const* d_in, const int* in_sizes, int n_in,
                              void* d_out, int out_size, void* d_ws, size_t ws_size,
                              hipStream_t stream) {
    const float* H    = (const float*)d_in[0];   // [N_src, 128]
    const float* W    = (const float*)d_in[1];   // [128, 128]
    const float* b    = (const float*)d_in[2];   // [128]
    const int*   esrc = (const int*)d_in[3];     // [E]
    const int*   edst = (const int*)d_in[4];     // [E]
    const int    E     = in_sizes[3];
    const int    n_dst = out_size / D;
    const int    nsrc_elems = in_sizes[0];       // N_src * 128
    const int    n_src = nsrc_elems / D;

    float* out = (float*)d_out;

    // ws: Wt | counts(padded) | ovcnt(pad) | ovd | ovs | buckets | aggb | WHb
    char* p = (char*)d_ws;
    unsigned short* Wt = (unsigned short*)p;  p += 128 * 128 * sizeof(unsigned short);
    int* counts = (int*)p;  p += (size_t)n_dst * CSTRIDE * 4;
    int* ovcnt  = (int*)p;  p += 256;            // zeroed together with counts
    int* ovd    = (int*)p;  p += (size_t)OVCAP * 4;
    int* ovs    = (int*)p;  p += (size_t)OVCAP * 4;
    int* buckets= (int*)p;  p += (size_t)n_dst * BCAP * 4;
    size_t agg_off = (((size_t)(p - (char*)d_ws)) + 255) & ~(size_t)255;
    unsigned short* aggb = (unsigned short*)((char*)d_ws + agg_off);
    size_t wh_off = (agg_off + (size_t)n_dst * D * 2 + 255) & ~(size_t)255;
    bool use_wh = (ws_size >= wh_off + (size_t)nsrc_elems * 2);
    unsigned short* WHb = (unsigned short*)((char*)d_ws + wh_off);

    // Zero counts+ovcnt AND transpose W->Wt bf16 in one dispatch.
    int nz4 = (n_dst * CSTRIDE + 64) / 4;
    int gz = nz4 > 8192 ? nz4 : 8192;
    zero_wt_kernel<<<(gz + 255) / 256, 256, 0, stream>>>(W, Wt, counts, nz4);

    if (use_wh) {
        int G = (n_src + 63) / 64;
        int Ge = (E + 511) / 512;
        if (Ge > G) G = Ge;
        prep_gemm_kernel<<<G, 256, 0, stream>>>(
            H, n_src, Wt, WHb, esrc, edst, E, counts, buckets, ovcnt, ovd, ovs);
        agg_finalize_kernel<<<(n_dst + 3) / 4, 256, 0, stream>>>(
            (const uint4*)WHb, buckets, counts, ovcnt, ovd, ovs, b, out, n_dst);
    } else {
        prep_fb_kernel<<<(E + 255) / 256, 256, 0, stream>>>(
            esrc, edst, E, counts, buckets, ovcnt, ovd, ovs);
        aggregate_kernel_f32<<<(n_dst + 3) / 4, 256, 0, stream>>>(
            H, buckets, counts, ovcnt, ovd, ovs, aggb, n_dst);
        gemm_finalize_kernel<<<(n_dst + 63) / 64, 256, 0, stream>>>(
            aggb, Wt, b, counts, out, n_dst);
    }
}

// Round 8
// 158.011 us; speedup vs baseline: 1.1313x; 1.0164x over previous
//
#include <hip/hip_runtime.h>

#define D 128
#define LDA 136     // bf16 elems per LDS row (+8 pad)
#define BCAP 64     // bucket capacity per dst (max degree ~35 for this data)
#define CSTRIDE 16  // counts padded: 1 counter per 64B line
#define OVCAP 65536 // overflow list capacity (correct fallback, empty in practice)

typedef __attribute__((ext_vector_type(8))) short bf16x8;
typedef __attribute__((ext_vector_type(4))) float f32x4;
typedef __attribute__((ext_vector_type(4))) unsigned int u32x4;

static __device__ __forceinline__ unsigned short f2bf(float f) {
    unsigned u = __float_as_uint(f);
    unsigned r = 0x7fffu + ((u >> 16) & 1u);   // round-to-nearest-even
    return (unsigned short)((u + r) >> 16);
}
static __device__ __forceinline__ float bflo(unsigned u) { return __uint_as_float(u << 16); }
static __device__ __forceinline__ float bfhi(unsigned u) { return __uint_as_float(u & 0xffff0000u); }

// ---------------------------------------------------------------------------
// zero_wt: replaces hipMemsetAsync (same dispatch count). Zeros counts +
// ovcnt with vector stores AND writes Wt[n][k] = bf16(W[k][n]) with
// COALESCED dword stores. (round-4 lesson: in-kernel LDS transpose = 32-way
// bank conflict, ~20us.)
// ---------------------------------------------------------------------------
__global__ __launch_bounds__(256) void zero_wt_kernel(
    const float* __restrict__ W, unsigned short* __restrict__ Wt,
    int* __restrict__ counts, int nz4)
{
    int i = blockIdx.x * 256 + threadIdx.x;
    if (i < nz4) ((u32x4*)counts)[i] = (u32x4){0u, 0u, 0u, 0u};
    if (i < 8192) {                          // 2 consecutive k per thread
        int n = i >> 6, k2 = (i & 63) << 1;
        unsigned lo = f2bf(W[(size_t)k2 * 128 + n]);
        unsigned hi = f2bf(W[(size_t)(k2 + 1) * 128 + n]);
        ((unsigned*)Wt)[(size_t)n * 64 + (k2 >> 1)] = lo | (hi << 16);
    }
}

// ---------------------------------------------------------------------------
// prep_gemm v4 (round-7 verified, 48us): two-pass half-W GEMM. Edge atomics
// first; Wsh half staged in 17408B LDS (round-6 lesson: B-frags from global
// put L2 latency on MFMA critical path); A-loads before barrier; per-wave
// bf16 Csh bounce; PLAIN WHb stores (round-3 lesson); bucket stores last.
// ---------------------------------------------------------------------------
__global__ __launch_bounds__(256, 6) void prep_gemm_kernel(
    const float* __restrict__ H, int n_src,
    const unsigned short* __restrict__ Wt, unsigned short* __restrict__ WHb,
    const int* __restrict__ esrc, const int* __restrict__ edst, int E,
    int* __restrict__ counts, int* __restrict__ buckets,
    int* __restrict__ ovcnt, int* __restrict__ ovd, int* __restrict__ ovs)
{
    __shared__ __align__(16) unsigned short Wsh[64 * LDA];   // 17408 B; Csh overlay

    const int tid = threadIdx.x, bid = blockIdx.x;
    const int gt = (int)gridDim.x * 256;

    // --- edges: loads + atomics issued first ---
    int e0 = bid * 256 + tid, e1 = e0 + gt;
    bool h0 = (e0 < E), h1 = (e1 < E);
    int d0 = 0, s0 = 0, d1 = 0, s1 = 0, c0 = 0, c1 = 0;
    if (h0) { d0 = __builtin_nontemporal_load(edst + e0);
              s0 = __builtin_nontemporal_load(esrc + e0); }
    if (h1) { d1 = __builtin_nontemporal_load(edst + e1);
              s1 = __builtin_nontemporal_load(esrc + e1); }
    if (h0) c0 = atomicAdd(&counts[(size_t)d0 * CSTRIDE], 1);
    if (h1) c1 = atomicAdd(&counts[(size_t)d1 * CSTRIDE], 1);

    const int lane = tid & 63, wvid = tid >> 6;
    const int fl = lane & 15, quad = lane >> 4;
    const int rowbase = bid * 64;
    const int m0 = wvid * 16;
    const bool doG = (rowbase < n_src);

    // --- stage Wsh half 0 (cols 0..63): b128, conflict-light ---
#pragma unroll
    for (int t = 0; t < 4; ++t) {
        int i = tid + t * 256;
        int nn = i >> 4, k8 = (i & 15) << 3;
        *(uint4*)&Wsh[nn * LDA + k8] = ((const uint4*)Wt)[nn * 16 + (i & 15)];
    }

    // --- A-loads issued before barrier: HBM latency drains with staging ---
    int arow = rowbase + m0 + fl;
    bool rok = doG && (arow < n_src);
    const f32x4* H4 = (const f32x4*)H;
    size_t base = (size_t)(rok ? arow : 0) * 32 + quad * 2;
    f32x4 z = (f32x4){0.f, 0.f, 0.f, 0.f};
    f32x4 av0 = z, av1 = z, av2 = z, av3 = z, av4 = z, av5 = z, av6 = z, av7 = z;
    if (rok) {
        av0 = H4[base +  0]; av1 = H4[base +  1];
        av2 = H4[base +  8]; av3 = H4[base +  9];
        av4 = H4[base + 16]; av5 = H4[base + 17];
        av6 = H4[base + 24]; av7 = H4[base + 25];
    }
    __syncthreads();

    f32x4 cacc[8];
#pragma unroll
    for (int n = 0; n < 8; ++n) cacc[n] = (f32x4){0.f, 0.f, 0.f, 0.f};

#define PACK_A(a, v0, v1)                                                    \
    { a[0] = (short)f2bf(v0.x); a[1] = (short)f2bf(v0.y);                    \
      a[2] = (short)f2bf(v0.z); a[3] = (short)f2bf(v0.w);                    \
      a[4] = (short)f2bf(v1.x); a[5] = (short)f2bf(v1.y);                    \
      a[6] = (short)f2bf(v1.z); a[7] = (short)f2bf(v1.w); }
#define MSTEP(a, KC, NL, CI)                                                  \
    { bf16x8 bf = *(const bf16x8*)&Wsh[((NL) * 16 + fl) * LDA + (KC) + quad * 8]; \
      cacc[CI] = __builtin_amdgcn_mfma_f32_16x16x32_bf16(a, bf, cacc[CI], 0, 0, 0); }

    bf16x8 a0, a1, a2, a3;
    PACK_A(a0, av0, av1) PACK_A(a1, av2, av3)
    PACK_A(a2, av4, av5) PACK_A(a3, av6, av7)

    if (doG) {
#pragma unroll
        for (int nl = 0; nl < 4; ++nl) {
            MSTEP(a0, 0, nl, nl) MSTEP(a1, 32, nl, nl)
            MSTEP(a2, 64, nl, nl) MSTEP(a3, 96, nl, nl)
        }
    }
    __syncthreads();   // Wsh half-0 dead

    // --- stage Wsh half 1 (cols 64..127) ---
#pragma unroll
    for (int t = 0; t < 4; ++t) {
        int i = tid + t * 256;
        int nn = i >> 4, k8 = (i & 15) << 3;
        *(uint4*)&Wsh[nn * LDA + k8] = ((const uint4*)Wt)[(64 + nn) * 16 + (i & 15)];
    }
    __syncthreads();

    if (doG) {
#pragma unroll
        for (int nl = 0; nl < 4; ++nl) {
            MSTEP(a0, 0, nl, nl + 4) MSTEP(a1, 32, nl, nl + 4)
            MSTEP(a2, 64, nl, nl + 4) MSTEP(a3, 96, nl, nl + 4)
        }
    }
    __syncthreads();   // Wsh dead; overlay Csh (per-wave slices, no more barriers)
#undef PACK_A
#undef MSTEP

    if (doG) {
        unsigned short* Csh = Wsh;   // [64][LDA] bf16 overlay
        // per-wave bf16 C-bounce (own 16-row slice; no cross-wave sharing)
#pragma unroll
        for (int n = 0; n < 8; ++n) {
            int col = n * 16 + fl;
#pragma unroll
            for (int r = 0; r < 4; ++r)
                Csh[(m0 + quad * 4 + r) * LDA + col] = f2bf(cacc[n][r]);
        }
        // coalesced store of this wave's rows (same-wave LDS RAW: compiler
        // inserts lgkmcnt; no barrier needed)
#pragma unroll
        for (int t = 0; t < 4; ++t) {
            int c = lane + t * 64;
            int row = m0 + (c >> 4), chunk = c & 15;
            size_t gr = (size_t)rowbase + row;
            if (gr < (size_t)n_src) {
                u32x4 v = *(const u32x4*)&Csh[row * LDA + chunk * 8];
                ((u32x4*)WHb)[gr * 16 + chunk] = v;   // PLAIN: keep L3-resident
            }
        }
    }

    // --- bucket stores (atomic results landed long ago) ---
    if (h0) {
        if (c0 < BCAP) buckets[(size_t)d0 * BCAP + c0] = s0;
        else { int o = atomicAdd(ovcnt, 1); if (o < OVCAP) { ovd[o] = d0; ovs[o] = s0; } }
    }
    if (h1) {
        if (c1 < BCAP) buckets[(size_t)d1 * BCAP + c1] = s1;
        else { int o = atomicAdd(ovcnt, 1); if (o < OVCAP) { ovd[o] = d1; ovs[o] = s1; } }
    }
    // cold remainder (only if E > 2*grid threads; empty here)
    for (int e = e0 + 2 * gt; e < E; e += gt) {
        int dd = edst[e], ss = esrc[e];
        int cc = atomicAdd(&counts[(size_t)dd * CSTRIDE], 1);
        if (cc < BCAP) buckets[(size_t)dd * BCAP + cc] = ss;
        else { int o = atomicAdd(ovcnt, 1); if (o < OVCAP) { ovd[o] = dd; ovs[o] = ss; } }
    }
}

// ---------------------------------------------------------------------------
// agg_finalize v2: one wave per dst. NEW: the first 16 edges' gather loads
// are issued BACK-TO-BACK with clamped indices (dead slots read the row the
// previous group just fetched -> L1 hit, weight 0) — raises in-flight loads
// from ~3 (old 8-main+4-tail shape at avg deg 12) to min(m,16). Deg>16
// falls through to the old verified 8-wide loop. counts/buckets reads are
// non-temporal (read-once; preserve L2/L3 for WHb). out = relu(sum/max(deg,1)
// + (deg>0?b:0)) written nt (write-once). No LDS -> full occupancy.
// ---------------------------------------------------------------------------
__global__ __launch_bounds__(256) void agg_finalize_kernel(
    const uint4* __restrict__ WHb, const int* __restrict__ buckets,
    const int* __restrict__ counts, const int* __restrict__ ovcnt,
    const int* __restrict__ ovd, const int* __restrict__ ovs,
    const float* __restrict__ b, float* __restrict__ out, int n_dst)
{
    int dst = blockIdx.x * 4 + (threadIdx.x >> 6);
    if (dst >= n_dst) return;
    int lane = threadIdx.x & 63;
    int dg = __builtin_nontemporal_load(counts + (size_t)dst * CSTRIDE);
    int m = dg < BCAP ? dg : BCAP;
    int nov = *ovcnt; if (nov > OVCAP) nov = OVCAP;
    int idx = (lane < m)
        ? __builtin_nontemporal_load(buckets + (size_t)dst * BCAP + lane) : 0;

    const int ql = lane & 15, quad = lane >> 4;
    float acc[8] = {0, 0, 0, 0, 0, 0, 0, 0};

    if (m > 0) {
        // --- edges 0..15: all loads issued together (MLP = min(m,16)) ---
        int c0 = quad, c1 = quad + 4, c2 = quad + 8, c3 = quad + 12;
        int l0 = c0 < m ? c0 : m - 1;
        int l1 = c1 < m ? c1 : m - 1;
        int l2 = c2 < m ? c2 : m - 1;
        int l3 = c3 < m ? c3 : m - 1;
        int s0 = __shfl(idx, l0), s1 = __shfl(idx, l1);
        int s2 = __shfl(idx, l2), s3 = __shfl(idx, l3);
        uint4 h0 = WHb[(size_t)s0 * 16 + ql];
        uint4 h1 = WHb[(size_t)s1 * 16 + ql];
        uint4 h2 = WHb[(size_t)s2 * 16 + ql];
        uint4 h3 = WHb[(size_t)s3 * 16 + ql];
        float w0 = (c0 < m) ? 1.f : 0.f, w1 = (c1 < m) ? 1.f : 0.f;
        float w2 = (c2 < m) ? 1.f : 0.f, w3 = (c3 < m) ? 1.f : 0.f;
        acc[0] = w0*bflo(h0.x) + w1*bflo(h1.x) + w2*bflo(h2.x) + w3*bflo(h3.x);
        acc[1] = w0*bfhi(h0.x) + w1*bfhi(h1.x) + w2*bfhi(h2.x) + w3*bfhi(h3.x);
        acc[2] = w0*bflo(h0.y) + w1*bflo(h1.y) + w2*bflo(h2.y) + w3*bflo(h3.y);
        acc[3] = w0*bfhi(h0.y) + w1*bfhi(h1.y) + w2*bfhi(h2.y) + w3*bfhi(h3.y);
        acc[4] = w0*bflo(h0.z) + w1*bflo(h1.z) + w2*bflo(h2.z) + w3*bflo(h3.z);
        acc[5] = w0*bfhi(h0.z) + w1*bfhi(h1.z) + w2*bfhi(h2.z) + w3*bfhi(h3.z);
        acc[6] = w0*bflo(h0.w) + w1*bflo(h1.w) + w2*bflo(h2.w) + w3*bflo(h3.w);
        acc[7] = w0*bfhi(h0.w) + w1*bfhi(h1.w) + w2*bfhi(h2.w) + w3*bfhi(h3.w);
    }

    // --- rare deep-degree remainder (m > 16): verified 8-wide loop ---
    int j = 16;
    for (; j + 8 <= m; j += 8) {
        int sA = __shfl(idx, j + quad);
        int sB = __shfl(idx, j + 4 + quad);
        uint4 ha = WHb[(size_t)sA * 16 + ql];
        uint4 hb = WHb[(size_t)sB * 16 + ql];
        acc[0] += bflo(ha.x) + bflo(hb.x); acc[1] += bfhi(ha.x) + bfhi(hb.x);
        acc[2] += bflo(ha.y) + bflo(hb.y); acc[3] += bfhi(ha.y) + bfhi(hb.y);
        acc[4] += bflo(ha.z) + bflo(hb.z); acc[5] += bfhi(ha.z) + bfhi(hb.z);
        acc[6] += bflo(ha.w) + bflo(hb.w); acc[7] += bfhi(ha.w) + bfhi(hb.w);
    }
    for (; j < m; j += 4) {                      // predicated tail
        int jj = j + quad;
        int s = __shfl(idx, jj < m ? jj : m - 1);
        uint4 hv = WHb[(size_t)s * 16 + ql];
        float w = (jj < m) ? 1.f : 0.f;
        acc[0] += w * bflo(hv.x); acc[1] += w * bfhi(hv.x);
        acc[2] += w * bflo(hv.y); acc[3] += w * bfhi(hv.y);
        acc[4] += w * bflo(hv.z); acc[5] += w * bfhi(hv.z);
        acc[6] += w * bflo(hv.w); acc[7] += w * bfhi(hv.w);
    }
    for (int k = quad; k < nov; k += 4) {        // overflow (empty normally)
        if (ovd[k] == dst) {
            uint4 hv = WHb[(size_t)ovs[k] * 16 + ql];
            acc[0] += bflo(hv.x); acc[1] += bfhi(hv.x);
            acc[2] += bflo(hv.y); acc[3] += bfhi(hv.y);
            acc[4] += bflo(hv.z); acc[5] += bfhi(hv.z);
            acc[6] += bflo(hv.w); acc[7] += bfhi(hv.w);
        }
    }
#pragma unroll
    for (int k = 0; k < 8; ++k) {
        acc[k] += __shfl_xor(acc[k], 16);
        acc[k] += __shfl_xor(acc[k], 32);
    }
    if (quad == 0) {
        float inv  = 1.0f / (float)(dg > 1 ? dg : 1);
        float gate = (dg > 0) ? 1.0f : 0.0f;
        const f32x4* b4 = (const f32x4*)b;
        f32x4 b0 = b4[ql * 2], b1 = b4[ql * 2 + 1];
        f32x4 o0, o1;
        o0.x = fmaxf(acc[0] * inv + b0.x * gate, 0.f);
        o0.y = fmaxf(acc[1] * inv + b0.y * gate, 0.f);
        o0.z = fmaxf(acc[2] * inv + b0.z * gate, 0.f);
        o0.w = fmaxf(acc[3] * inv + b0.w * gate, 0.f);
        o1.x = fmaxf(acc[4] * inv + b1.x * gate, 0.f);
        o1.y = fmaxf(acc[5] * inv + b1.y * gate, 0.f);
        o1.z = fmaxf(acc[6] * inv + b1.z * gate, 0.f);
        o1.w = fmaxf(acc[7] * inv + b1.w * gate, 0.f);
        f32x4* op = (f32x4*)out + (size_t)dst * 32 + ql * 2;
        __builtin_nontemporal_store(o0, op);
        __builtin_nontemporal_store(o1, op + 1);
    }
}

// ---------------------------------------------------------------------------
// Fallback path (workspace too small for WHb): edges-only prep, f32 gather,
// MFMA gemm_finalize (Wt comes from zero_wt). Verified in earlier rounds.
// ---------------------------------------------------------------------------
__global__ __launch_bounds__(256) void prep_fb_kernel(
    const int* __restrict__ esrc, const int* __restrict__ edst, int E,
    int* __restrict__ counts, int* __restrict__ buckets,
    int* __restrict__ ovcnt, int* __restrict__ ovd, int* __restrict__ ovs)
{
    int i = blockIdx.x * 256 + threadIdx.x;
    if (i >= E) return;
    int d = edst[i], s = esrc[i];
    int c = atomicAdd(&counts[(size_t)d * CSTRIDE], 1);
    if (c < BCAP) buckets[(size_t)d * BCAP + c] = s;
    else { int o = atomicAdd(ovcnt, 1); if (o < OVCAP) { ovd[o] = d; ovs[o] = s; } }
}

__global__ __launch_bounds__(256) void aggregate_kernel_f32(
    const float* __restrict__ H,
    const int* __restrict__ buckets, const int* __restrict__ counts,
    const int* __restrict__ ovcnt, const int* __restrict__ ovd,
    const int* __restrict__ ovs, unsigned short* __restrict__ aggb, int n_dst)
{
    int dst = blockIdx.x * 4 + (threadIdx.x >> 6);
    if (dst >= n_dst) return;
    int lane = threadIdx.x & 63;
    int dg = counts[(size_t)dst * CSTRIDE];
    int m = dg < BCAP ? dg : BCAP;
    int nov = *ovcnt; if (nov > OVCAP) nov = OVCAP;
    int idx = (lane < m) ? buckets[(size_t)dst * BCAP + lane] : 0;

    const int hl = lane & 31, half = lane >> 5;
    const float4* H4 = (const float4*)H;
    float acc[4] = {0, 0, 0, 0};
    int j = 0;
    for (; j + 4 <= m; j += 4) {
        int sA = __shfl(idx, j + half);
        int sB = __shfl(idx, j + 2 + half);
        float4 va = H4[(size_t)sA * 32 + hl];
        float4 vb = H4[(size_t)sB * 32 + hl];
        acc[0] += va.x + vb.x; acc[1] += va.y + vb.y;
        acc[2] += va.z + vb.z; acc[3] += va.w + vb.w;
    }
    for (; j < m; j += 2) {
        int jj = j + half;
        int s = __shfl(idx, jj < m ? jj : m - 1);
        float4 v = H4[(size_t)s * 32 + hl];
        float w = (jj < m) ? 1.f : 0.f;
        acc[0] += w * v.x; acc[1] += w * v.y;
        acc[2] += w * v.z; acc[3] += w * v.w;
    }
    for (int k = half; k < nov; k += 2) {
        if (ovd[k] == dst) {
            float4 v = H4[(size_t)ovs[k] * 32 + hl];
            acc[0] += v.x; acc[1] += v.y; acc[2] += v.z; acc[3] += v.w;
        }
    }
#pragma unroll
    for (int k = 0; k < 4; ++k) acc[k] += __shfl_xor(acc[k], 32);
    if (half == 0) {
        uint2 o;
        o.x = (unsigned)f2bf(acc[0]) | ((unsigned)f2bf(acc[1]) << 16);
        o.y = (unsigned)f2bf(acc[2]) | ((unsigned)f2bf(acc[3]) << 16);
        ((uint2*)aggb)[(size_t)dst * 32 + hl] = o;
    }
}

__global__ __launch_bounds__(256) void gemm_finalize_kernel(
    const unsigned short* __restrict__ aggb, const unsigned short* __restrict__ Wt,
    const float* __restrict__ b, const int* __restrict__ counts,
    float* __restrict__ out, int n_dst)
{
    __shared__ __align__(16) unsigned char smem[52224];
    unsigned short* Ash = (unsigned short*)smem;                   // [64][LDA]
    unsigned short* Wsh = (unsigned short*)(smem + 64 * LDA * 2);  // [128][LDA]
    float* Csh = (float*)smem;                                     // [64][132]

    const int tid  = threadIdx.x;
    const int lane = tid & 63, wv = tid >> 6;
    const size_t row0 = (size_t)blockIdx.x * 64;

#pragma unroll
    for (int t = 0; t < 4; ++t) {
        int i = tid + t * 256;
        int r = i >> 4, k8 = (i & 15) << 3;
        size_t gr = row0 + r;
        uint4 v = (gr < (size_t)n_dst) ? ((const uint4*)aggb)[gr * 16 + (i & 15)]
                                       : make_uint4(0, 0, 0, 0);
        *(uint4*)&Ash[r * LDA + k8] = v;
    }
#pragma unroll
    for (int t = 0; t < 8; ++t) {
        int i = tid + t * 256;
        int n = i >> 4, k8 = (i & 15) << 3;
        *(uint4*)&Wsh[n * LDA + k8] = ((const uint4*)Wt)[i];
    }
    __syncthreads();

    const int m0 = wv * 16;
    const int fl = lane & 15, quad = lane >> 4;

    f32x4 cacc[8];
#pragma unroll
    for (int n = 0; n < 8; ++n) cacc[n] = (f32x4){0.f, 0.f, 0.f, 0.f};

#pragma unroll
    for (int kc = 0; kc < 128; kc += 32) {
        bf16x8 a = *(const bf16x8*)&Ash[(m0 + fl) * LDA + kc + quad * 8];
#pragma unroll
        for (int n = 0; n < 8; ++n) {
            bf16x8 bf = *(const bf16x8*)&Wsh[(n * 16 + fl) * LDA + kc + quad * 8];
            cacc[n] = __builtin_amdgcn_mfma_f32_16x16x32_bf16(a, bf, cacc[n], 0, 0, 0);
        }
    }

    float inv[4], gate[4];
#pragma unroll
    for (int r = 0; r < 4; ++r) {
        size_t gr = row0 + m0 + quad * 4 + r;
        int dg = (gr < (size_t)n_dst) ? counts[gr * CSTRIDE] : 0;
        inv[r]  = 1.0f / (float)(dg > 1 ? dg : 1);
        gate[r] = (dg > 0) ? 1.0f : 0.0f;
    }
    __syncthreads();   // Ash/Wsh dead; reuse as Csh

#pragma unroll
    for (int n = 0; n < 8; ++n) {
        int col = n * 16 + fl;
        float bc = b[col];
#pragma unroll
        for (int r = 0; r < 4; ++r) {
            float v = cacc[n][r] * inv[r] + bc * gate[r];
            Csh[(m0 + quad * 4 + r) * 132 + col] = fmaxf(v, 0.0f);
        }
    }
    __syncthreads();

#pragma unroll
    for (int t = 0; t < 8; ++t) {
        int i = tid + t * 256;
        int rr = i >> 5, c4 = i & 31;
        size_t gr = row0 + rr;
        if (gr < (size_t)n_dst) {
            f32x4 vout = *(f32x4*)&Csh[rr * 132 + c4 * 4];
            __builtin_nontemporal_store(vout, (f32x4*)out + gr * (D / 4) + c4);
        }
    }
}

extern "C" void kernel_launch(void* const* d_in, const int* in_sizes, int n_in,
                              void* d_out, int out_size, void* d_ws, size_t ws_size,
                              hipStream_t stream) {
    const float* H    = (const float*)d_in[0];   // [N_src, 128]
    const float* W    = (const float*)d_in[1];   // [128, 128]
    const float* b    = (const float*)d_in[2];   // [128]
    const int*   esrc = (const int*)d_in[3];     // [E]
    const int*   edst = (const int*)d_in[4];     // [E]
    const int    E     = in_sizes[3];
    const int    n_dst = out_size / D;
    const int    nsrc_elems = in_sizes[0];       // N_src * 128
    const int    n_src = nsrc_elems / D;

    float* out = (float*)d_out;

    // ws: Wt | counts(padded) | ovcnt(pad) | ovd | ovs | buckets | aggb | WHb
    char* p = (char*)d_ws;
    unsigned short* Wt = (unsigned short*)p;  p += 128 * 128 * sizeof(unsigned short);
    int* counts = (int*)p;  p += (size_t)n_dst * CSTRIDE * 4;
    int* ovcnt  = (int*)p;  p += 256;            // zeroed together with counts
    int* ovd    = (int*)p;  p += (size_t)OVCAP * 4;
    int* ovs    = (int*)p;  p += (size_t)OVCAP * 4;
    int* buckets= (int*)p;  p += (size_t)n_dst * BCAP * 4;
    size_t agg_off = (((size_t)(p - (char*)d_ws)) + 255) & ~(size_t)255;
    unsigned short* aggb = (unsigned short*)((char*)d_ws + agg_off);
    size_t wh_off = (agg_off + (size_t)n_dst * D * 2 + 255) & ~(size_t)255;
    bool use_wh = (ws_size >= wh_off + (size_t)nsrc_elems * 2);
    unsigned short* WHb = (unsigned short*)((char*)d_ws + wh_off);

    // Zero counts+ovcnt AND transpose W->Wt bf16 in one dispatch.
    int nz4 = (n_dst * CSTRIDE + 64) / 4;
    int gz = nz4 > 8192 ? nz4 : 8192;
    zero_wt_kernel<<<(gz + 255) / 256, 256, 0, stream>>>(W, Wt, counts, nz4);

    if (use_wh) {
        int G = (n_src + 63) / 64;
        int Ge = (E + 511) / 512;
        if (Ge > G) G = Ge;
        prep_gemm_kernel<<<G, 256, 0, stream>>>(
            H, n_src, Wt, WHb, esrc, edst, E, counts, buckets, ovcnt, ovd, ovs);
        agg_finalize_kernel<<<(n_dst + 3) / 4, 256, 0, stream>>>(
            (const uint4*)WHb, buckets, counts, ovcnt, ovd, ovs, b, out, n_dst);
    } else {
        prep_fb_kernel<<<(E + 255) / 256, 256, 0, stream>>>(
            esrc, edst, E, counts, buckets, ovcnt, ovd, ovs);
        aggregate_kernel_f32<<<(n_dst + 3) / 4, 256, 0, stream>>>(
            H, buckets, counts, ovcnt, ovd, ovs, aggb, n_dst);
        gemm_finalize_kernel<<<(n_dst + 63) / 64, 256, 0, stream>>>(
            aggb, Wt, b, counts, out, n_dst);
    }
}